// Round 8
// baseline (592.910 us; speedup 1.0000x reference)
//
#include <hip/hip_runtime.h>

#define E_EDGES   800000
#define NN_NODES  50000
#define NODE_DIM  128
#define EDGE_DIM  64
#define KDIM      320
#define BM        64       // edges per block (main)
#define BN        64       // nodes per block (pcompute)
#define SWA       64       // As row stride (f16), XOR-swizzled
#define SMH       136      // msgBuf row stride (f16): 68 dwords == 4 mod 32 -> 2-way max
#define SX        136      // Xs row stride (f16) in pcompute
#define SO        264      // Os row stride (f16) in pcompute
#define SAF       72       // fallback As stride
#define SLOTK     32       // receiver-half LDS cache depth (typ. nslots ~5-6)
#define THREADS   512
#define W4UNITS   20480    // float4 units in W_val||W_mul
#define NSCAN     98       // ceil(50000/512)

typedef _Float16 half8 __attribute__((ext_vector_type(8)));
typedef _Float16 half2t __attribute__((ext_vector_type(2)));
typedef __fp16   fp16x2 __attribute__((ext_vector_type(2)));
typedef float    f32x4 __attribute__((ext_vector_type(4)));

__device__ __forceinline__ unsigned short f2h(float f) {
    _Float16 h = (_Float16)f;
    return __builtin_bit_cast(unsigned short, h);
}
__device__ __forceinline__ float h2f(unsigned short u) {
    return (float)__builtin_bit_cast(_Float16, u);
}
// packed f32x2 -> f16x2 (single v_cvt_pkrtz_f32_f16)
__device__ __forceinline__ unsigned pkrtz(float a, float b) {
    fp16x2 r = __builtin_amdgcn_cvt_pkrtz(a, b);
    return __builtin_bit_cast(unsigned, r);
}

// ---- prep: cast W fp32->f16  +  receiver histogram ----
__global__ void prep(const float* __restrict__ wv,
                     const float* __restrict__ wm,
                     const int* __restrict__ ei,
                     unsigned short* __restrict__ Wc,
                     unsigned* __restrict__ cnt) {
    int i = blockIdx.x * blockDim.x + threadIdx.x;
    if (i < W4UNITS) {
        const int n4h = (NODE_DIM * KDIM) / 4;   // 10240
        const float* src = (i < n4h) ? wv : wm;
        int j = (i < n4h) ? i : i - n4h;
        float4 f = ((const float4*)src)[j];
        uint2 o;
        o.x = pkrtz(f.x, f.y);
        o.y = pkrtz(f.z, f.w);
        ((uint2*)Wc)[i] = o;
    } else {
        int e = i - W4UNITS;
        if (e < E_EDGES) atomicAdd(&cnt[ei[E_EDGES + e]], 1u);
    }
}

// ---- exclusive scan over 50000 counts ----
__global__ void scan1(const unsigned* __restrict__ cnt,
                      unsigned* __restrict__ offs,
                      unsigned* __restrict__ bsum) {
    __shared__ unsigned s[512];
    int tid = threadIdx.x;
    int i = blockIdx.x * 512 + tid;
    unsigned v = (i < NN_NODES) ? cnt[i] : 0u;
    s[tid] = v; __syncthreads();
    for (int off = 1; off < 512; off <<= 1) {
        unsigned t = (tid >= off) ? s[tid - off] : 0u;
        __syncthreads();
        s[tid] += t;
        __syncthreads();
    }
    if (i < NN_NODES) offs[i] = s[tid] - v;
    if (tid == 511) bsum[blockIdx.x] = s[511];
}

__global__ void scan2(unsigned* __restrict__ bsum) {
    __shared__ unsigned s[128];
    int tid = threadIdx.x;
    unsigned v = (tid < NSCAN) ? bsum[tid] : 0u;
    s[tid] = v; __syncthreads();
    for (int off = 1; off < 128; off <<= 1) {
        unsigned t = (tid >= off) ? s[tid - off] : 0u;
        __syncthreads();
        s[tid] += t;
        __syncthreads();
    }
    if (tid < NSCAN) bsum[tid] = s[tid] - v;
}

// ---- scatter: fill perm with edge ids, receiver-sorted (block offset fused) ----
__global__ void scatter_k(const int* __restrict__ ei,
                          unsigned* __restrict__ offs,
                          const unsigned* __restrict__ bsum,
                          unsigned* __restrict__ perm) {
    int e = blockIdx.x * blockDim.x + threadIdx.x;
    if (e >= E_EDGES) return;
    int r = ei[E_EDGES + e];
    unsigned p = atomicAdd(&offs[r], 1u) + bsum[r >> 9];
    perm[p] = (unsigned)e;
}

// ---- per-node projection precompute ----
// Ph[node][512] f16:  [nhalf=0: sender-part (bias folded) | nhalf=1: receiver-part]
// within each 256-half: channel c in [0,128), packed (val_c, gate_c) at c*2 + vg.
__global__ void __launch_bounds__(THREADS, 2)
pcompute(const float* __restrict__ x,
         const unsigned short* __restrict__ Wc,
         const float* __restrict__ bval,
         const float* __restrict__ bmul,
         unsigned short* __restrict__ Ph)
{
    __shared__ unsigned short Xs[BN * SX];   // 17408 B
    __shared__ unsigned short Os[BN * SO];   // 33792 B
    const int tid  = threadIdx.x;
    const int n0   = blockIdx.x * BN;
    const int lane = tid & 63;
    const int wid  = tid >> 6;
    const int wm   = wid & 1;
    const int wn   = wid >> 1;
    const int q    = lane >> 4;
    const int l16  = lane & 15;

#pragma unroll
    for (int i = 0; i < 2; ++i) {
        int u = tid + i * THREADS;
        int row = u >> 4, seg = u & 15;
        int node = n0 + row;
        if (node >= NN_NODES) node = NN_NODES - 1;
        const float* s = x + (size_t)node * NODE_DIM + seg * 8;
        float4 f0 = ((const float4*)s)[0];
        float4 f1 = ((const float4*)s)[1];
        uint4 v;
        v.x = pkrtz(f0.x, f0.y);
        v.y = pkrtz(f0.z, f0.w);
        v.z = pkrtz(f1.x, f1.y);
        v.w = pkrtz(f1.z, f1.w);
        *(uint4*)(&Xs[row * SX + seg * 8]) = v;
    }
    __syncthreads();

#pragma unroll
    for (int nhalf = 0; nhalf < 2; ++nhalf) {
        f32x4 acc[2][4];
        const f32x4 zero4 = {0.f, 0.f, 0.f, 0.f};
#pragma unroll
        for (int mt = 0; mt < 2; ++mt)
#pragma unroll
            for (int nt = 0; nt < 4; ++nt) acc[mt][nt] = zero4;

#pragma unroll
        for (int ks = 0; ks < 4; ++ks) {
            half8 a[2], b[4];
#pragma unroll
            for (int mt = 0; mt < 2; ++mt)
                a[mt] = *(const half8*)(&Xs[(wm * 32 + mt * 16 + l16) * SX + ks * 32 + q * 8]);
#pragma unroll
            for (int nt = 0; nt < 4; ++nt)
                b[nt] = *(const half8*)(Wc + (size_t)(wn * 64 + nt * 16 + l16) * KDIM
                                           + nhalf * 128 + ks * 32 + q * 8);
#pragma unroll
            for (int mt = 0; mt < 2; ++mt)
#pragma unroll
                for (int nt = 0; nt < 4; ++nt)
                    acc[mt][nt] = __builtin_amdgcn_mfma_f32_16x16x32_f16(
                        a[mt], b[nt], acc[mt][nt], 0, 0, 0);
        }

#pragma unroll
        for (int mt = 0; mt < 2; ++mt) {
#pragma unroll
            for (int nt = 0; nt < 4; ++nt) {
                int j  = wn * 64 + nt * 16 + l16;
                int c  = j & 127;
                int vg = j >> 7;
                float bb = 0.f;
                if (nhalf == 0) bb = vg ? bmul[c] : bval[c];
#pragma unroll
                for (int r = 0; r < 4; ++r) {
                    int row = wm * 32 + mt * 16 + q * 4 + r;
                    Os[row * SO + c * 2 + vg] = f2h(acc[mt][nt][r] + bb);
                }
            }
        }
        __syncthreads();

#pragma unroll
        for (int i = 0; i < 4; ++i) {
            int u = tid + i * THREADS;
            int row = u >> 5, seg = u & 31;
            int node = n0 + row;
            if (node < NN_NODES) {
                uint4 v = *(const uint4*)(&Os[row * SO + seg * 8]);
                *(uint4*)(Ph + (size_t)node * 512 + nhalf * 256 + seg * 8) = v;
            }
        }
        __syncthreads();
    }
}

// ---- sorted main: ef-GEMM + gather projections + activation + segmented reduce ----
__global__ void __launch_bounds__(THREADS, 4)
cgc_sorted(const unsigned short* __restrict__ Ph,  // [NN][512] f16
           const int* __restrict__ ei,             // [2][E]
           const float* __restrict__ ef,           // [E][64] fp32
           const unsigned short* __restrict__ Wc,  // [256][320] f16
           const unsigned* __restrict__ perm,      // [E] receiver-sorted edge ids
           float* __restrict__ out)                // [NN][128] fp32 (zeroed)
{
    __shared__ unsigned short msgBuf[BM * SMH];    // 17408 B ; front 8192 B aliased as As
    __shared__ unsigned slotR[SLOTK * NODE_DIM];   // 16384 B receiver-half cache
    __shared__ int  eIds[BM];
    __shared__ int  sIdx[BM];
    __shared__ int  slotOf[BM];
    __shared__ int  runStart[BM + 1];
    __shared__ int  slotRecv[BM];
    __shared__ int  nslotsS;

    unsigned short* As = (unsigned short*)msgBuf;  // [BM][SWA] f16, XOR-swizzled

    const int tid  = threadIdx.x;
    const int e0   = blockIdx.x * BM;
    const int lane = tid & 63;
    const int wid  = tid >> 6;
    const int wm   = wid & 1;
    const int wn   = wid >> 1;
    const int q    = lane >> 4;
    const int l16  = lane & 15;

    // wave 0: sorted edge ids, endpoints, ballot run detection
    if (tid < BM) {
        int e = (int)perm[e0 + tid];
        eIds[tid] = e;
        int sN = ei[e];
        int rN = ei[E_EDGES + e];
        sIdx[tid] = sN;
        int prev = __shfl_up(rN, 1);
        int flag = (tid == 0) || (prev != rN);
        unsigned long long m = __ballot(flag);
        int slot = __popcll(m & (((unsigned long long)2 << tid) - 1)) - 1;
        slotOf[tid] = slot;
        if (flag) { runStart[slot] = tid; slotRecv[slot] = rN; }
        if (tid == BM - 1) {
            int ns = (int)__popcll(m);
            nslotsS = ns;
            runStart[ns] = BM;
        }
    }
    __syncthreads();   // eIds/run info ready

    // stage ef rows (via perm): 64 rows x 64 f32 -> f16, XOR-swizzled store
    {
        int row = tid >> 3, seg = tid & 7;
        const float* s = ef + (size_t)eIds[row] * EDGE_DIM + seg * 8;
        float4 f0 = ((const float4*)s)[0];
        float4 f1 = ((const float4*)s)[1];
        uint4 v;
        v.x = pkrtz(f0.x, f0.y);
        v.y = pkrtz(f0.z, f0.w);
        v.z = pkrtz(f1.x, f1.y);
        v.w = pkrtz(f1.z, f1.w);
        int inner = (seg * 8) ^ ((row & 7) << 3);
        *(uint4*)(&As[row * SWA + inner]) = v;
    }

    // preload receiver-half rows for the first SLOTK slots (coalesced 512B/slot).
    // 13x dedup of the receiver Ph gather (edges in a run share rN).
    {
        int ns = nslotsS < SLOTK ? nslotsS : SLOTK;
        for (int u = tid; u < ns * 32; u += THREADS) {
            int s = u >> 5, seg = u & 31;
            uint4 v = ((const uint4*)(Ph + ((size_t)slotRecv[s] << 9) + 256))[seg];
            *(uint4*)(&slotR[s * NODE_DIM + seg * 4]) = v;
        }
    }

    // B fragments from L2-resident Wc (edge-feature K-slice)
    const int nb0 = wn * 32;
    const int nbase[4] = { nb0, nb0 + 16, 128 + nb0, 128 + nb0 + 16 };
    half8 b[2][4];
#pragma unroll
    for (int ks = 0; ks < 2; ++ks)
#pragma unroll
        for (int nt = 0; nt < 4; ++nt)
            b[ks][nt] = *(const half8*)(Wc + (size_t)(nbase[nt] + l16) * KDIM
                                           + 256 + ks * 32 + q * 8);

    f32x4 acc[2][4];
    const f32x4 zero4 = {0.f, 0.f, 0.f, 0.f};
#pragma unroll
    for (int mt = 0; mt < 2; ++mt)
#pragma unroll
        for (int nt = 0; nt < 4; ++nt) acc[mt][nt] = zero4;

    __syncthreads();   // As + slotR staged

#pragma unroll
    for (int ks = 0; ks < 2; ++ks) {
        half8 a[2];
#pragma unroll
        for (int mt = 0; mt < 2; ++mt) {
            int row = wm * 32 + mt * 16 + l16;
            int inner = (ks * 32 + q * 8) ^ ((row & 7) << 3);
            a[mt] = *(const half8*)(&As[row * SWA + inner]);
        }
#pragma unroll
        for (int mt = 0; mt < 2; ++mt)
#pragma unroll
            for (int nt = 0; nt < 4; ++nt)
                acc[mt][nt] = __builtin_amdgcn_mfma_f32_16x16x32_f16(
                    a[mt], b[ks][nt], acc[mt][nt], 0, 0, 0);
    }

    __syncthreads();   // done reading As -> safe to overwrite as msgBuf

    // epilogue: sender gather (global) + receiver from LDS cache, activation,
    // f16 store to message tile
#pragma unroll
    for (int mt = 0; mt < 2; ++mt) {
#pragma unroll
        for (int r = 0; r < 4; ++r) {
            int row = wm * 32 + mt * 16 + q * 4 + r;
            int sN = sIdx[row];
            int slot = slotOf[row];
            const unsigned* pS = (const unsigned*)(Ph + ((size_t)sN << 9));
            const unsigned* pR = (slot < SLOTK)
                ? &slotR[slot * NODE_DIM]
                : (const unsigned*)(Ph + ((size_t)slotRecv[slot] << 9) + 256);
#pragma unroll
            for (int ct = 0; ct < 2; ++ct) {
                int c = wn * 32 + ct * 16 + l16;
                half2t hs = __builtin_bit_cast(half2t, pS[c]);
                half2t hr = __builtin_bit_cast(half2t, pR[c]);
                half2t t  = hs + hr;                       // v_pk_add_f16
                float v = acc[mt][ct][r]     + (float)t.x;
                float g = acc[mt][ct + 2][r] + (float)t.y;
                float sp  = fmaxf(v, 0.f) + __logf(1.f + __expf(-fabsf(v)));
                float sig = __builtin_amdgcn_rcpf(1.f + __expf(-g));
                msgBuf[row * SMH + c] = f2h(sp * sig);     // unique (row,c)
            }
        }
    }
    __syncthreads();   // message tile complete

    // segmented flush: one global atomic per (distinct receiver, channel)
    const int nslots = nslotsS;
    for (int idx = tid; idx < nslots * NODE_DIM; idx += THREADS) {
        int s = idx >> 7, c = idx & 127;
        int rs = runStart[s], re = runStart[s + 1];
        float sum = 0.f;
        const unsigned short* p = &msgBuf[rs * SMH + c];
        for (int row = rs; row < re; ++row) { sum += h2f(*p); p += SMH; }
        atomicAdd(out + (size_t)slotRecv[s] * NODE_DIM + c, sum);
    }
}

// ---- fallback main (R2-verified): per-edge global atomics ----
__global__ void __launch_bounds__(THREADS, 4)
cgc_atomic(const unsigned short* __restrict__ Ph,
           const int* __restrict__ ei,
           const float* __restrict__ ef,
           const unsigned short* __restrict__ Wc,
           float* __restrict__ out)
{
    __shared__ unsigned short As[BM * SAF];
    __shared__ int sIdx[BM];
    __shared__ int rIdx[BM];

    const int tid  = threadIdx.x;
    const int e0   = blockIdx.x * BM;
    const int lane = tid & 63;
    const int wid  = tid >> 6;
    const int wm   = wid & 1;
    const int wn   = wid >> 1;
    const int q    = lane >> 4;
    const int l16  = lane & 15;

    if (tid < BM) {
        sIdx[tid] = ei[e0 + tid];
        rIdx[tid] = ei[E_EDGES + e0 + tid];
    }
    {
        int row = tid >> 3, seg = tid & 7;
        const float* s = ef + (size_t)(e0 + row) * EDGE_DIM + seg * 8;
        float4 f0 = ((const float4*)s)[0];
        float4 f1 = ((const float4*)s)[1];
        uint4 v;
        v.x = pkrtz(f0.x, f0.y);
        v.y = pkrtz(f0.z, f0.w);
        v.z = pkrtz(f1.x, f1.y);
        v.w = pkrtz(f1.z, f1.w);
        *(uint4*)(&As[row * SAF + seg * 8]) = v;
    }
    const int nb0 = wn * 32;
    const int nbase[4] = { nb0, nb0 + 16, 128 + nb0, 128 + nb0 + 16 };
    half8 b[2][4];
#pragma unroll
    for (int ks = 0; ks < 2; ++ks)
#pragma unroll
        for (int nt = 0; nt < 4; ++nt)
            b[ks][nt] = *(const half8*)(Wc + (size_t)(nbase[nt] + l16) * KDIM
                                           + 256 + ks * 32 + q * 8);
    f32x4 acc[2][4];
    const f32x4 zero4 = {0.f, 0.f, 0.f, 0.f};
#pragma unroll
    for (int mt = 0; mt < 2; ++mt)
#pragma unroll
        for (int nt = 0; nt < 4; ++nt) acc[mt][nt] = zero4;
    __syncthreads();
#pragma unroll
    for (int ks = 0; ks < 2; ++ks) {
        half8 a[2];
#pragma unroll
        for (int mt = 0; mt < 2; ++mt)
            a[mt] = *(const half8*)(&As[(wm * 32 + mt * 16 + l16) * SAF + ks * 32 + q * 8]);
#pragma unroll
        for (int mt = 0; mt < 2; ++mt)
#pragma unroll
            for (int nt = 0; nt < 4; ++nt)
                acc[mt][nt] = __builtin_amdgcn_mfma_f32_16x16x32_f16(
                    a[mt], b[ks][nt], acc[mt][nt], 0, 0, 0);
    }
#pragma unroll
    for (int mt = 0; mt < 2; ++mt) {
#pragma unroll
        for (int r = 0; r < 4; ++r) {
            int row = wm * 32 + mt * 16 + q * 4 + r;
            int sN = sIdx[row];
            int rN = rIdx[row];
            const unsigned* pS = (const unsigned*)(Ph + ((size_t)sN << 9));
            const unsigned* pR = (const unsigned*)(Ph + ((size_t)rN << 9) + 256);
#pragma unroll
            for (int ct = 0; ct < 2; ++ct) {
                int c = wn * 32 + ct * 16 + l16;
                half2t hs = __builtin_bit_cast(half2t, pS[c]);
                half2t hr = __builtin_bit_cast(half2t, pR[c]);
                half2t t  = hs + hr;
                float v = acc[mt][ct][r]     + (float)t.x;
                float g = acc[mt][ct + 2][r] + (float)t.y;
                float sp  = fmaxf(v, 0.f) + __logf(1.f + __expf(-fabsf(v)));
                float sig = __builtin_amdgcn_rcpf(1.f + __expf(-g));
                atomicAdd(out + (size_t)rN * NODE_DIM + c, sp * sig);
            }
        }
    }
}

// ============================ LAUNCH ============================

extern "C" void kernel_launch(void* const* d_in, const int* in_sizes, int n_in,
                              void* d_out, int out_size, void* d_ws, size_t ws_size,
                              hipStream_t stream) {
    const float* x  = (const float*)d_in[0];
    const int*   ei = (const int*)d_in[1];
    const float* ef = (const float*)d_in[2];
    const float* Wv = (const float*)d_in[3];
    const float* bv = (const float*)d_in[4];
    const float* Wm = (const float*)d_in[5];
    const float* bm = (const float*)d_in[6];
    float* out = (float*)d_out;

    // workspace layout
    const size_t oWc   = 0;                    // 160 KB (pad 256 KB)
    const size_t oPh   = 262144;               // 51.2 MB
    const size_t oCnt  = oPh  + 51200000;      // 200 KB (pad)
    const size_t oOffs = oCnt + 200704;        // 200 KB (pad)
    const size_t oBsum = oOffs + 200704;       // 512 B
    const size_t oPerm = oBsum + 512;          // 3.2 MB
    const size_t need_sorted = oPerm + (size_t)E_EDGES * 4;   // ~55.1 MB

    unsigned short* Wc = (unsigned short*)((char*)d_ws + oWc);
    unsigned short* Ph = (unsigned short*)((char*)d_ws + oPh);

    hipMemsetAsync(d_out, 0, (size_t)NN_NODES * NODE_DIM * sizeof(float), stream);

    if (ws_size >= need_sorted) {
        unsigned* cnt  = (unsigned*)((char*)d_ws + oCnt);
        unsigned* offs = (unsigned*)((char*)d_ws + oOffs);
        unsigned* bsum = (unsigned*)((char*)d_ws + oBsum);
        unsigned* perm = (unsigned*)((char*)d_ws + oPerm);

        hipMemsetAsync(cnt, 0, NN_NODES * sizeof(unsigned), stream);

        const int totalPrep = W4UNITS + E_EDGES;              // 820480
        prep<<<(totalPrep + 255) / 256, 256, 0, stream>>>(Wv, Wm, ei, Wc, cnt);
        scan1<<<NSCAN, 512, 0, stream>>>(cnt, offs, bsum);
        scan2<<<1, 128, 0, stream>>>(bsum);
        scatter_k<<<(E_EDGES + 255) / 256, 256, 0, stream>>>(ei, offs, bsum, perm);

        pcompute<<<(NN_NODES + BN - 1) / BN, THREADS, 0, stream>>>(x, Wc, bv, bm, Ph);
        cgc_sorted<<<E_EDGES / BM, THREADS, 0, stream>>>(Ph, ei, ef, Wc, perm, out);
    } else {
        // fallback: R2-verified unsorted path (per-edge atomics)
        prep<<<(W4UNITS + 255) / 256, 256, 0, stream>>>(Wv, Wm, ei, Wc,
                                                        (unsigned*)((char*)d_ws + oPh));
        pcompute<<<(NN_NODES + BN - 1) / BN, THREADS, 0, stream>>>(x, Wc, bv, bm, Ph);
        cgc_atomic<<<E_EDGES / BM, THREADS, 0, stream>>>(Ph, ei, ef, Wc, out);
    }
}

// Round 9
// 561.821 us; speedup vs baseline: 1.0553x; 1.0553x over previous
//
#include <hip/hip_runtime.h>

#define E_EDGES   800000
#define NN_NODES  50000
#define NODE_DIM  128
#define EDGE_DIM  64
#define KDIM      320
#define BM        64       // edges per block (main)
#define BN        64       // nodes per block (pcompute)
#define SWA       64       // As row stride (f16), XOR-swizzled
#define SMH       136      // msgBuf row stride (f16): 68 dwords == 4 mod 32 -> 2-way max
#define SX        136      // Xs row stride (f16) in pcompute
#define SO        264      // Os row stride (f16) in pcompute
#define SAF       72       // fallback As stride
#define THREADS   512
#define W4UNITS   20480    // float4 units in W_val||W_mul
#define NSCAN     98       // ceil(50000/512)

typedef _Float16 half8 __attribute__((ext_vector_type(8)));
typedef _Float16 half2t __attribute__((ext_vector_type(2)));
typedef __fp16   fp16x2 __attribute__((ext_vector_type(2)));
typedef float    f32x4 __attribute__((ext_vector_type(4)));

__device__ __forceinline__ unsigned short f2h(float f) {
    _Float16 h = (_Float16)f;
    return __builtin_bit_cast(unsigned short, h);
}
__device__ __forceinline__ float h2f(unsigned short u) {
    return (float)__builtin_bit_cast(_Float16, u);
}
__device__ __forceinline__ unsigned pkrtz(float a, float b) {
    fp16x2 r = __builtin_amdgcn_cvt_pkrtz(a, b);
    return __builtin_bit_cast(unsigned, r);
}

// ---- prep: cast W fp32->f16  +  receiver histogram ----
__global__ void prep(const float* __restrict__ wv,
                     const float* __restrict__ wm,
                     const int* __restrict__ ei,
                     unsigned short* __restrict__ Wc,
                     unsigned* __restrict__ cnt) {
    int i = blockIdx.x * blockDim.x + threadIdx.x;
    if (i < W4UNITS) {
        const int n4h = (NODE_DIM * KDIM) / 4;   // 10240
        const float* src = (i < n4h) ? wv : wm;
        int j = (i < n4h) ? i : i - n4h;
        float4 f = ((const float4*)src)[j];
        uint2 o;
        o.x = pkrtz(f.x, f.y);
        o.y = pkrtz(f.z, f.w);
        ((uint2*)Wc)[i] = o;
    } else {
        int e = i - W4UNITS;
        if (e < E_EDGES) atomicAdd(&cnt[ei[E_EDGES + e]], 1u);
    }
}

// ---- exclusive scan over 50000 counts ----
__global__ void scan1(const unsigned* __restrict__ cnt,
                      unsigned* __restrict__ offs,
                      unsigned* __restrict__ bsum) {
    __shared__ unsigned s[512];
    int tid = threadIdx.x;
    int i = blockIdx.x * 512 + tid;
    unsigned v = (i < NN_NODES) ? cnt[i] : 0u;
    s[tid] = v; __syncthreads();
    for (int off = 1; off < 512; off <<= 1) {
        unsigned t = (tid >= off) ? s[tid - off] : 0u;
        __syncthreads();
        s[tid] += t;
        __syncthreads();
    }
    if (i < NN_NODES) offs[i] = s[tid] - v;
    if (tid == 511) bsum[blockIdx.x] = s[511];
}

__global__ void scan2(unsigned* __restrict__ bsum) {
    __shared__ unsigned s[128];
    int tid = threadIdx.x;
    unsigned v = (tid < NSCAN) ? bsum[tid] : 0u;
    s[tid] = v; __syncthreads();
    for (int off = 1; off < 128; off <<= 1) {
        unsigned t = (tid >= off) ? s[tid - off] : 0u;
        __syncthreads();
        s[tid] += t;
        __syncthreads();
    }
    if (tid < NSCAN) bsum[tid] = s[tid] - v;
}

// ---- scatter (esr): store sorted {e, sender, receiver} triples ----
// Removes the main kernel's scattered ei[e] gather (~100 MB of 64B-line
// amplified HBM fetch, R8 counter audit).
__global__ void scatter_esr(const int* __restrict__ ei,
                            unsigned* __restrict__ offs,
                            const unsigned* __restrict__ bsum,
                            uint4* __restrict__ esr) {
    int e = blockIdx.x * blockDim.x + threadIdx.x;
    if (e >= E_EDGES) return;
    int s = ei[e];
    int r = ei[E_EDGES + e];
    unsigned p = atomicAdd(&offs[r], 1u) + bsum[r >> 9];
    esr[p] = make_uint4((unsigned)e, (unsigned)s, (unsigned)r, 0u);
}

// ---- scatter (perm-only fallback layout) ----
__global__ void scatter_k(const int* __restrict__ ei,
                          unsigned* __restrict__ offs,
                          const unsigned* __restrict__ bsum,
                          unsigned* __restrict__ perm) {
    int e = blockIdx.x * blockDim.x + threadIdx.x;
    if (e >= E_EDGES) return;
    int r = ei[E_EDGES + e];
    unsigned p = atomicAdd(&offs[r], 1u) + bsum[r >> 9];
    perm[p] = (unsigned)e;
}

// ---- per-node projection precompute ----
// Ph[node][512] f16:  [nhalf=0: sender-part (bias folded) | nhalf=1: receiver-part]
// within each 256-half: channel c in [0,128), packed (val_c, gate_c) at c*2 + vg.
__global__ void __launch_bounds__(THREADS, 2)
pcompute(const float* __restrict__ x,
         const unsigned short* __restrict__ Wc,
         const float* __restrict__ bval,
         const float* __restrict__ bmul,
         unsigned short* __restrict__ Ph)
{
    __shared__ unsigned short Xs[BN * SX];   // 17408 B
    __shared__ unsigned short Os[BN * SO];   // 33792 B
    const int tid  = threadIdx.x;
    const int n0   = blockIdx.x * BN;
    const int lane = tid & 63;
    const int wid  = tid >> 6;
    const int wm   = wid & 1;
    const int wn   = wid >> 1;
    const int q    = lane >> 4;
    const int l16  = lane & 15;

#pragma unroll
    for (int i = 0; i < 2; ++i) {
        int u = tid + i * THREADS;
        int row = u >> 4, seg = u & 15;
        int node = n0 + row;
        if (node >= NN_NODES) node = NN_NODES - 1;
        const float* s = x + (size_t)node * NODE_DIM + seg * 8;
        float4 f0 = ((const float4*)s)[0];
        float4 f1 = ((const float4*)s)[1];
        uint4 v;
        v.x = pkrtz(f0.x, f0.y);
        v.y = pkrtz(f0.z, f0.w);
        v.z = pkrtz(f1.x, f1.y);
        v.w = pkrtz(f1.z, f1.w);
        *(uint4*)(&Xs[row * SX + seg * 8]) = v;
    }
    __syncthreads();

#pragma unroll
    for (int nhalf = 0; nhalf < 2; ++nhalf) {
        f32x4 acc[2][4];
        const f32x4 zero4 = {0.f, 0.f, 0.f, 0.f};
#pragma unroll
        for (int mt = 0; mt < 2; ++mt)
#pragma unroll
            for (int nt = 0; nt < 4; ++nt) acc[mt][nt] = zero4;

#pragma unroll
        for (int ks = 0; ks < 4; ++ks) {
            half8 a[2], b[4];
#pragma unroll
            for (int mt = 0; mt < 2; ++mt)
                a[mt] = *(const half8*)(&Xs[(wm * 32 + mt * 16 + l16) * SX + ks * 32 + q * 8]);
#pragma unroll
            for (int nt = 0; nt < 4; ++nt)
                b[nt] = *(const half8*)(Wc + (size_t)(wn * 64 + nt * 16 + l16) * KDIM
                                           + nhalf * 128 + ks * 32 + q * 8);
#pragma unroll
            for (int mt = 0; mt < 2; ++mt)
#pragma unroll
                for (int nt = 0; nt < 4; ++nt)
                    acc[mt][nt] = __builtin_amdgcn_mfma_f32_16x16x32_f16(
                        a[mt], b[nt], acc[mt][nt], 0, 0, 0);
        }

#pragma unroll
        for (int mt = 0; mt < 2; ++mt) {
#pragma unroll
            for (int nt = 0; nt < 4; ++nt) {
                int j  = wn * 64 + nt * 16 + l16;
                int c  = j & 127;
                int vg = j >> 7;
                float bb = 0.f;
                if (nhalf == 0) bb = vg ? bmul[c] : bval[c];
#pragma unroll
                for (int r = 0; r < 4; ++r) {
                    int row = wm * 32 + mt * 16 + q * 4 + r;
                    Os[row * SO + c * 2 + vg] = f2h(acc[mt][nt][r] + bb);
                }
            }
        }
        __syncthreads();

#pragma unroll
        for (int i = 0; i < 4; ++i) {
            int u = tid + i * THREADS;
            int row = u >> 5, seg = u & 31;
            int node = n0 + row;
            if (node < NN_NODES) {
                uint4 v = *(const uint4*)(&Os[row * SO + seg * 8]);
                *(uint4*)(Ph + (size_t)node * 512 + nhalf * 256 + seg * 8) = v;
            }
        }
        __syncthreads();
    }
}

// ---- sorted main: ef-GEMM + batched projection gather + activation + segmented reduce ----
template<bool USE_ESR>
__global__ void __launch_bounds__(THREADS, 4)
cgc_sorted(const unsigned short* __restrict__ Ph,  // [NN][512] f16
           const int* __restrict__ ei,             // [2][E]
           const float* __restrict__ ef,           // [E][64] fp32
           const unsigned short* __restrict__ Wc,  // [256][320] f16
           const unsigned* __restrict__ perm,      // [E] sorted edge ids (perm mode)
           const uint4* __restrict__ esr,          // [E] {e,s,r,0} (esr mode)
           float* __restrict__ out)                // [NN][128] fp32 (zeroed)
{
    __shared__ unsigned short msgBuf[BM * SMH];    // 17408 B ; front 8192 B aliased as As
    __shared__ int  eIds[BM];
    __shared__ int  sIdx[BM];
    __shared__ int  rIdx[BM];
    __shared__ int  runStart[BM + 1];
    __shared__ int  slotRecv[BM];
    __shared__ int  nslotsS;

    unsigned short* As = (unsigned short*)msgBuf;  // [BM][SWA] f16, XOR-swizzled

    const int tid  = threadIdx.x;
    const int e0   = blockIdx.x * BM;
    const int lane = tid & 63;
    const int wid  = tid >> 6;
    const int wm   = wid & 1;
    const int wn   = wid >> 1;
    const int q    = lane >> 4;
    const int l16  = lane & 15;

    // wave 0: sorted edge triples, ballot run detection
    if (tid < BM) {
        int e, sN, rN;
        if (USE_ESR) {
            uint4 t = esr[e0 + tid];
            e = (int)t.x; sN = (int)t.y; rN = (int)t.z;
        } else {
            e = (int)perm[e0 + tid];
            sN = ei[e];
            rN = ei[E_EDGES + e];
        }
        eIds[tid] = e;
        sIdx[tid] = sN;
        rIdx[tid] = rN;
        int prev = __shfl_up(rN, 1);
        int flag = (tid == 0) || (prev != rN);
        unsigned long long m = __ballot(flag);
        int slot = __popcll(m & (((unsigned long long)2 << tid) - 1)) - 1;
        if (flag) { runStart[slot] = tid; slotRecv[slot] = rN; }
        if (tid == BM - 1) {
            int ns = (int)__popcll(m);
            nslotsS = ns;
            runStart[ns] = BM;
        }
    }
    __syncthreads();   // idx/run info ready

    // stage ef rows: 64 rows x 64 f32 -> f16, XOR-swizzled store
    {
        int row = tid >> 3, seg = tid & 7;
        const float* s = ef + (size_t)eIds[row] * EDGE_DIM + seg * 8;
        float4 f0 = ((const float4*)s)[0];
        float4 f1 = ((const float4*)s)[1];
        uint4 v;
        v.x = pkrtz(f0.x, f0.y);
        v.y = pkrtz(f0.z, f0.w);
        v.z = pkrtz(f1.x, f1.y);
        v.w = pkrtz(f1.z, f1.w);
        int inner = (seg * 8) ^ ((row & 7) << 3);
        *(uint4*)(&As[row * SWA + inner]) = v;
    }

    // B fragments from L2-resident Wc (edge-feature K-slice)
    const int nb0 = wn * 32;
    const int nbase[4] = { nb0, nb0 + 16, 128 + nb0, 128 + nb0 + 16 };
    half8 b[2][4];
#pragma unroll
    for (int ks = 0; ks < 2; ++ks)
#pragma unroll
        for (int nt = 0; nt < 4; ++nt)
            b[ks][nt] = *(const half8*)(Wc + (size_t)(nbase[nt] + l16) * KDIM
                                           + 256 + ks * 32 + q * 8);

    f32x4 acc[2][4];
    const f32x4 zero4 = {0.f, 0.f, 0.f, 0.f};
#pragma unroll
    for (int mt = 0; mt < 2; ++mt)
#pragma unroll
        for (int nt = 0; nt < 4; ++nt) acc[mt][nt] = zero4;

    __syncthreads();   // As staged

#pragma unroll
    for (int ks = 0; ks < 2; ++ks) {
        half8 a[2];
#pragma unroll
        for (int mt = 0; mt < 2; ++mt) {
            int row = wm * 32 + mt * 16 + l16;
            int inner = (ks * 32 + q * 8) ^ ((row & 7) << 3);
            a[mt] = *(const half8*)(&As[row * SWA + inner]);
        }
#pragma unroll
        for (int mt = 0; mt < 2; ++mt)
#pragma unroll
            for (int nt = 0; nt < 4; ++nt)
                acc[mt][nt] = __builtin_amdgcn_mfma_f32_16x16x32_f16(
                    a[mt], b[ks][nt], acc[mt][nt], 0, 0, 0);
    }

    __syncthreads();   // done reading As -> safe to overwrite as msgBuf

    // ---- epilogue phase 1: batched projection gather (32 loads in flight) ----
    unsigned usv[2][4][2], urv[2][4][2];
#pragma unroll
    for (int mt = 0; mt < 2; ++mt) {
#pragma unroll
        for (int r = 0; r < 4; ++r) {
            int row = wm * 32 + mt * 16 + q * 4 + r;
            const unsigned* pS = (const unsigned*)(Ph + ((size_t)sIdx[row] << 9));
            const unsigned* pR = (const unsigned*)(Ph + ((size_t)rIdx[row] << 9) + 256);
#pragma unroll
            for (int ct = 0; ct < 2; ++ct) {
                int c = wn * 32 + ct * 16 + l16;
                usv[mt][r][ct] = pS[c];
                urv[mt][r][ct] = pR[c];
            }
        }
    }

    // ---- epilogue phase 2: activation math + f16 store to msg tile ----
#pragma unroll
    for (int mt = 0; mt < 2; ++mt) {
#pragma unroll
        for (int r = 0; r < 4; ++r) {
            int row = wm * 32 + mt * 16 + q * 4 + r;
#pragma unroll
            for (int ct = 0; ct < 2; ++ct) {
                int c = wn * 32 + ct * 16 + l16;
                half2t hs = __builtin_bit_cast(half2t, usv[mt][r][ct]);
                half2t hr = __builtin_bit_cast(half2t, urv[mt][r][ct]);
                half2t t  = hs + hr;                       // v_pk_add_f16
                float v = acc[mt][ct][r]     + (float)t.x;
                float g = acc[mt][ct + 2][r] + (float)t.y;
                float sp  = fmaxf(v, 0.f) + __logf(1.f + __expf(-fabsf(v)));
                float sig = __builtin_amdgcn_rcpf(1.f + __expf(-g));
                msgBuf[row * SMH + c] = f2h(sp * sig);     // unique (row,c)
            }
        }
    }
    __syncthreads();   // message tile complete

    // segmented flush: paired-dword LDS reads, one atomic per (receiver, channel)
    const int nslots = nslotsS;
    for (int idx = tid; idx < nslots * 64; idx += THREADS) {
        int s = idx >> 6, cp = idx & 63;       // channel pair
        int rs = runStart[s], re = runStart[s + 1];
        float s0 = 0.f, s1 = 0.f;
        const unsigned* p = (const unsigned*)&msgBuf[rs * SMH + cp * 2];
        for (int row = rs; row < re; ++row) {
            half2t h = __builtin_bit_cast(half2t, *p);
            s0 += (float)h.x; s1 += (float)h.y;
            p += SMH / 2;
        }
        float* o = out + ((size_t)slotRecv[s] << 7) + cp * 2;
        atomicAdd(o,     s0);
        atomicAdd(o + 1, s1);
    }
}

// ---- fallback main (R2-verified): per-edge global atomics ----
__global__ void __launch_bounds__(THREADS, 4)
cgc_atomic(const unsigned short* __restrict__ Ph,
           const int* __restrict__ ei,
           const float* __restrict__ ef,
           const unsigned short* __restrict__ Wc,
           float* __restrict__ out)
{
    __shared__ unsigned short As[BM * SAF];
    __shared__ int sIdx[BM];
    __shared__ int rIdx[BM];

    const int tid  = threadIdx.x;
    const int e0   = blockIdx.x * BM;
    const int lane = tid & 63;
    const int wid  = tid >> 6;
    const int wm   = wid & 1;
    const int wn   = wid >> 1;
    const int q    = lane >> 4;
    const int l16  = lane & 15;

    if (tid < BM) {
        sIdx[tid] = ei[e0 + tid];
        rIdx[tid] = ei[E_EDGES + e0 + tid];
    }
    {
        int row = tid >> 3, seg = tid & 7;
        const float* s = ef + (size_t)(e0 + row) * EDGE_DIM + seg * 8;
        float4 f0 = ((const float4*)s)[0];
        float4 f1 = ((const float4*)s)[1];
        uint4 v;
        v.x = pkrtz(f0.x, f0.y);
        v.y = pkrtz(f0.z, f0.w);
        v.z = pkrtz(f1.x, f1.y);
        v.w = pkrtz(f1.z, f1.w);
        *(uint4*)(&As[row * SAF + seg * 8]) = v;
    }
    const int nb0 = wn * 32;
    const int nbase[4] = { nb0, nb0 + 16, 128 + nb0, 128 + nb0 + 16 };
    half8 b[2][4];
#pragma unroll
    for (int ks = 0; ks < 2; ++ks)
#pragma unroll
        for (int nt = 0; nt < 4; ++nt)
            b[ks][nt] = *(const half8*)(Wc + (size_t)(nbase[nt] + l16) * KDIM
                                           + 256 + ks * 32 + q * 8);
    f32x4 acc[2][4];
    const f32x4 zero4 = {0.f, 0.f, 0.f, 0.f};
#pragma unroll
    for (int mt = 0; mt < 2; ++mt)
#pragma unroll
        for (int nt = 0; nt < 4; ++nt) acc[mt][nt] = zero4;
    __syncthreads();
#pragma unroll
    for (int ks = 0; ks < 2; ++ks) {
        half8 a[2];
#pragma unroll
        for (int mt = 0; mt < 2; ++mt)
            a[mt] = *(const half8*)(&As[(wm * 32 + mt * 16 + l16) * SAF + ks * 32 + q * 8]);
#pragma unroll
        for (int mt = 0; mt < 2; ++mt)
#pragma unroll
            for (int nt = 0; nt < 4; ++nt)
                acc[mt][nt] = __builtin_amdgcn_mfma_f32_16x16x32_f16(
                    a[mt], b[ks][nt], acc[mt][nt], 0, 0, 0);
    }
#pragma unroll
    for (int mt = 0; mt < 2; ++mt) {
#pragma unroll
        for (int r = 0; r < 4; ++r) {
            int row = wm * 32 + mt * 16 + q * 4 + r;
            int sN = sIdx[row];
            int rN = rIdx[row];
            const unsigned* pS = (const unsigned*)(Ph + ((size_t)sN << 9));
            const unsigned* pR = (const unsigned*)(Ph + ((size_t)rN << 9) + 256);
#pragma unroll
            for (int ct = 0; ct < 2; ++ct) {
                int c = wn * 32 + ct * 16 + l16;
                half2t hs = __builtin_bit_cast(half2t, pS[c]);
                half2t hr = __builtin_bit_cast(half2t, pR[c]);
                half2t t  = hs + hr;
                float v = acc[mt][ct][r]     + (float)t.x;
                float g = acc[mt][ct + 2][r] + (float)t.y;
                float sp  = fmaxf(v, 0.f) + __logf(1.f + __expf(-fabsf(v)));
                float sig = __builtin_amdgcn_rcpf(1.f + __expf(-g));
                atomicAdd(out + (size_t)rN * NODE_DIM + c, sp * sig);
            }
        }
    }
}

// ============================ LAUNCH ============================

extern "C" void kernel_launch(void* const* d_in, const int* in_sizes, int n_in,
                              void* d_out, int out_size, void* d_ws, size_t ws_size,
                              hipStream_t stream) {
    const float* x  = (const float*)d_in[0];
    const int*   ei = (const int*)d_in[1];
    const float* ef = (const float*)d_in[2];
    const float* Wv = (const float*)d_in[3];
    const float* bv = (const float*)d_in[4];
    const float* Wm = (const float*)d_in[5];
    const float* bm = (const float*)d_in[6];
    float* out = (float*)d_out;

    // workspace layout
    const size_t oWc   = 0;                    // 160 KB (pad 256 KB)
    const size_t oPh   = 262144;               // 51.2 MB
    const size_t oCnt  = oPh  + 51200000;      // 200 KB (pad)
    const size_t oOffs = oCnt + 200704;        // 200 KB (pad)
    const size_t oBsum = oOffs + 200704;       // 512 B
    const size_t oEsr  = oBsum + 512;          // 12.8 MB (uint4/edge) or 3.2 MB (perm)
    const size_t need_esr  = oEsr + (size_t)E_EDGES * 16;  // ~64.7 MB
    const size_t need_perm = oEsr + (size_t)E_EDGES * 4;   // ~55.1 MB

    unsigned short* Wc = (unsigned short*)((char*)d_ws + oWc);
    unsigned short* Ph = (unsigned short*)((char*)d_ws + oPh);

    hipMemsetAsync(d_out, 0, (size_t)NN_NODES * NODE_DIM * sizeof(float), stream);

    if (ws_size >= need_perm) {
        unsigned* cnt  = (unsigned*)((char*)d_ws + oCnt);
        unsigned* offs = (unsigned*)((char*)d_ws + oOffs);
        unsigned* bsum = (unsigned*)((char*)d_ws + oBsum);

        hipMemsetAsync(cnt, 0, NN_NODES * sizeof(unsigned), stream);

        const int totalPrep = W4UNITS + E_EDGES;              // 820480
        prep<<<(totalPrep + 255) / 256, 256, 0, stream>>>(Wv, Wm, ei, Wc, cnt);
        scan1<<<NSCAN, 512, 0, stream>>>(cnt, offs, bsum);
        scan2<<<1, 128, 0, stream>>>(bsum);

        if (ws_size >= need_esr) {
            uint4* esr = (uint4*)((char*)d_ws + oEsr);
            scatter_esr<<<(E_EDGES + 255) / 256, 256, 0, stream>>>(ei, offs, bsum, esr);
            pcompute<<<(NN_NODES + BN - 1) / BN, THREADS, 0, stream>>>(x, Wc, bv, bm, Ph);
            cgc_sorted<true><<<E_EDGES / BM, THREADS, 0, stream>>>(
                Ph, ei, ef, Wc, nullptr, esr, out);
        } else {
            unsigned* perm = (unsigned*)((char*)d_ws + oEsr);
            scatter_k<<<(E_EDGES + 255) / 256, 256, 0, stream>>>(ei, offs, bsum, perm);
            pcompute<<<(NN_NODES + BN - 1) / BN, THREADS, 0, stream>>>(x, Wc, bv, bm, Ph);
            cgc_sorted<false><<<E_EDGES / BM, THREADS, 0, stream>>>(
                Ph, ei, ef, Wc, perm, nullptr, out);
        }
    } else {
        // fallback: R2-verified unsorted path (per-edge atomics)
        prep<<<(W4UNITS + 255) / 256, 256, 0, stream>>>(Wv, Wm, ei, Wc,
                                                        (unsigned*)((char*)d_ws + oPh));
        pcompute<<<(NN_NODES + BN - 1) / BN, THREADS, 0, stream>>>(x, Wc, bv, bm, Ph);
        cgc_atomic<<<E_EDGES / BM, THREADS, 0, stream>>>(Ph, ei, ef, Wc, out);
    }
}